// Round 2
// baseline (257.848 us; speedup 1.0000x reference)
//
#include <hip/hip_runtime.h>
#include <hip/hip_bf16.h>
#include <stdint.h>

typedef __attribute__((ext_vector_type(8))) short short8;
typedef __attribute__((ext_vector_type(4))) float f32x4;
typedef __attribute__((ext_vector_type(4))) float float4v;
typedef __attribute__((ext_vector_type(4))) unsigned short ushort4v;

#define DEVI static __device__ __forceinline__

constexpr int Bb = 16, Nn = 2048, Cc = 256, Dd = 256;

// ---------- bf16 helpers (explicit RNE, no dependence on hip_bf16 internals) ----------
DEVI unsigned short f2bf(float f) {
  uint32_t u = __float_as_uint(f);
  u = (u + 0x7fffu + ((u >> 16) & 1u)) >> 16;
  return (unsigned short)u;
}
DEVI float bf2f(unsigned short u) { return __uint_as_float(((uint32_t)u) << 16); }

DEVI void gl_lds16(const void* gsrc, void* ldst) {
  __builtin_amdgcn_global_load_lds(
      (const __attribute__((address_space(1))) unsigned int*)gsrc,
      (__attribute__((address_space(3))) unsigned int*)ldst, 16, 0, 0);
}

DEVI f32x4 mfma16(short8 a, short8 b, f32x4 c) {
  return __builtin_amdgcn_mfma_f32_16x16x32_bf16(a, b, c, 0, 0, 0);
}

// ---------- kernel 0a: split x (f32) -> xhi,xlo (bf16) ----------
__global__ void k_split_x(const float* __restrict__ x,
                          unsigned short* __restrict__ xhi,
                          unsigned short* __restrict__ xlo) {
  int i = blockIdx.x * 256 + threadIdx.x;  // 0 .. 2097151, 4 floats each
  float4v v = reinterpret_cast<const float4v*>(x)[i];
  ushort4v hi, lo;
#pragma unroll
  for (int j = 0; j < 4; ++j) {
    unsigned short h = f2bf(v[j]);
    hi[j] = h;
    lo[j] = f2bf(v[j] - bf2f(h));
  }
  reinterpret_cast<ushort4v*>(xhi)[i] = hi;
  reinterpret_cast<ushort4v*>(xlo)[i] = lo;
}

// ---------- kernel 0b: build Wsp[mat][d][768] = [Whi | Wlo | Whi] ----------
__global__ void k_split_w(const float* __restrict__ wq, const float* __restrict__ wk,
                          const float* __restrict__ wv, unsigned short* __restrict__ wsp) {
  int i = blockIdx.x * 256 + threadIdx.x;  // 0 .. 196607
  int mat = i >> 16;
  int rem = i & 65535;
  int d = rem >> 8, c = rem & 255;
  const float* w = (mat == 0) ? wq : ((mat == 1) ? wk : wv);
  float val = w[rem];
  unsigned short hi = f2bf(val);
  unsigned short lo = f2bf(val - bf2f(hi));
  unsigned short* o = wsp + (size_t)mat * (Dd * 768) + (size_t)d * 768 + c;
  o[0] = hi;
  o[256] = lo;
  o[512] = hi;
}

// ---------- kernel 1: QKV projection GEMM ----------
// out[m,d] = sum_{k'=0..767} A'[m,k'] * B'[k',d] + bias[d]
// A' = [xhi | xhi | xlo] (virtual), B' = Wsp rows. 128x128 tile, BK=64, 4 waves.
__global__ __launch_bounds__(256, 2) void k_qkv(
    const unsigned short* __restrict__ xhi, const unsigned short* __restrict__ xlo,
    const unsigned short* __restrict__ wsp,
    const float* __restrict__ bq, const float* __restrict__ bk, const float* __restrict__ bv,
    unsigned short* __restrict__ qhi, unsigned short* __restrict__ qlo,
    unsigned short* __restrict__ kkout, unsigned short* __restrict__ vt) {
  __shared__ __align__(16) unsigned short smem[17408];  // staging 32KB; V-transpose 128x136

  const int tid = threadIdx.x;
  const int m0 = blockIdx.x * 128;
  const int n0 = blockIdx.y * 128;
  const int mat = blockIdx.z;
  const unsigned short* wmat = wsp + (size_t)mat * (Dd * 768);
  const int wave = tid >> 6, lane = tid & 63;
  const int wr = wave >> 1, wc = wave & 1;
  const int l15 = lane & 15, lq = lane >> 4;

  f32x4 zero4 = {0.f, 0.f, 0.f, 0.f};
  f32x4 acc[4][4];
#pragma unroll
  for (int a = 0; a < 4; ++a)
#pragma unroll
    for (int b2 = 0; b2 < 4; ++b2) acc[a][b2] = zero4;

  char* As = (char*)smem;           // [128 rows][128B], XOR-swizzled
  char* Bs = (char*)smem + 16384;   // [128 rows][128B], XOR-swizzled

  for (int kc = 0; kc < 12; ++kc) {
    const unsigned short* asrc = (kc < 8) ? xhi : xlo;
    const int akc = (kc & 3) * 64;  // k-offset within 256
    // stage A: 16KB = 4 issues; LDS linear, global source pre-swizzled
#pragma unroll
    for (int i = 0; i < 4; ++i) {
      int p = i * 4096 + tid * 16;
      int row = p >> 7;
      int src_in_row = (p & 127) ^ ((row & 7) << 4);
      const char* g = (const char*)(asrc + (size_t)(m0 + row) * Cc + akc) + src_in_row;
      gl_lds16(g, As + p);
    }
    // stage B
#pragma unroll
    for (int i = 0; i < 4; ++i) {
      int p = i * 4096 + tid * 16;
      int row = p >> 7;
      int src_in_row = (p & 127) ^ ((row & 7) << 4);
      const char* g = (const char*)(wmat + (size_t)(n0 + row) * 768 + kc * 64) + src_in_row;
      gl_lds16(g, Bs + p);
    }
    __syncthreads();
#pragma unroll
    for (int ks = 0; ks < 2; ++ks) {
      short8 af[4], bfr[4];
#pragma unroll
      for (int mf = 0; mf < 4; ++mf) {
        int row = wr * 64 + mf * 16 + l15;
        int byte = (row * 128 + ks * 64 + lq * 16) ^ ((row & 7) << 4);
        af[mf] = *(const short8*)(As + byte);
      }
#pragma unroll
      for (int nf = 0; nf < 4; ++nf) {
        int row = wc * 64 + nf * 16 + l15;
        int byte = (row * 128 + ks * 64 + lq * 16) ^ ((row & 7) << 4);
        bfr[nf] = *(const short8*)(Bs + byte);
      }
#pragma unroll
      for (int mf = 0; mf < 4; ++mf)
#pragma unroll
        for (int nf = 0; nf < 4; ++nf) acc[mf][nf] = mfma16(af[mf], bfr[nf], acc[mf][nf]);
    }
    __syncthreads();
  }

  const float* bias = (mat == 0) ? bq : ((mat == 1) ? bk : bv);
  if (mat < 2) {
    unsigned short* hi_out = (mat == 0) ? qhi : kkout;
#pragma unroll
    for (int nf = 0; nf < 4; ++nf) {
      int col = n0 + wc * 64 + nf * 16 + l15;
      float bval = bias[col];
#pragma unroll
      for (int mf = 0; mf < 4; ++mf) {
        int grow = m0 + wr * 64 + mf * 16 + lq * 4;
#pragma unroll
        for (int r = 0; r < 4; ++r) {
          float v = acc[mf][nf][r] + bval;
          unsigned short h = f2bf(v);
          size_t off = (size_t)(grow + r) * Dd + col;
          hi_out[off] = h;
          if (mat == 0) qlo[off] = f2bf(v - bf2f(h));
        }
      }
    }
  } else {
    // V: transpose tile through LDS -> coalesced stores into vt[B][D][N]
    __syncthreads();
#pragma unroll
    for (int nf = 0; nf < 4; ++nf) {
      int dl = wc * 64 + nf * 16 + l15;
      float bval = bias[n0 + dl];
#pragma unroll
      for (int mf = 0; mf < 4; ++mf) {
        int nl = wr * 64 + mf * 16 + lq * 4;
#pragma unroll
        for (int r = 0; r < 4; ++r) smem[dl * 136 + nl + r] = f2bf(acc[mf][nf][r] + bval);
      }
    }
    __syncthreads();
    const int bbat = m0 >> 11, tok0 = m0 & 2047;
#pragma unroll
    for (int pss = 0; pss < 8; ++pss) {
      int idx = pss * 256 + tid;  // 16B unit index; 2048 total
      int dl = idx >> 4;
      int cu = idx & 15;
      short8 vval = *(const short8*)((const char*)smem + dl * 272 + cu * 16);
      size_t off = ((size_t)bbat * Dd + n0 + dl) * Nn + tok0 + cu * 8;
      *(short8*)(vt + off) = vval;
    }
  }
}

// ---------- kernel 2: flash attention ----------
// grid 512 blocks (1D, XCD-pinned), 256 threads = 4 waves, BQ=64, KV tile 64.
// Block i -> XCD i%8 (HW round-robin). XCD g owns batches {g, g+8}:
// 2 batches x (K+V = 2MB) = 4MB = one XCD's L2, so tile staging hits L2
// instead of thrashing to L3 (the round-1 bottleneck: 2.8 TB/s staging).
__global__ __launch_bounds__(256, 2) void k_attn(
    const unsigned short* __restrict__ qhi, const unsigned short* __restrict__ qlo,
    const unsigned short* __restrict__ kin, const unsigned short* __restrict__ vt,
    const int* __restrict__ vlen, float* __restrict__ out) {
  __shared__ __align__(16) char Ks[32768];            // [64 key][512B], swizzled
  __shared__ __align__(16) char Vs[32768];            // [256 d][128B], swizzled
  __shared__ __align__(16) unsigned short Ps[4][16 * 72];  // per-wave P [16 q][64+8 key]

  const int tid = threadIdx.x;
  const int wave = tid >> 6, lane = tid & 63;
  const int l15 = lane & 15, lq = lane >> 4;
  // XCD-pinned mapping: g = xcd, j = index within xcd's 64 blocks
  const int id = blockIdx.x;
  const int g = id & 7;
  const int j = id >> 3;           // 0..63
  const int b = g + 8 * (j >> 5);  // batches g, g+8
  const int q0 = (j & 31) * 64;
  const int L = vlen[b];
  const bool uni = (L == 0);
  const int Lk = uni ? Nn : L;
  const int ntiles = (Lk + 63) >> 6;

  // Q fragments in registers (hi+lo), rows = lane&15 of this wave's 16 rows
  const size_t qrow = (size_t)b * Nn + q0 + wave * 16 + l15;
  short8 qh[8], ql[8];
#pragma unroll
  for (int kt = 0; kt < 8; ++kt) {
    size_t off = qrow * Dd + kt * 32 + lq * 8;
    qh[kt] = *(const short8*)(qhi + off);
    ql[kt] = *(const short8*)(qlo + off);
  }

  f32x4 zero4 = {0.f, 0.f, 0.f, 0.f};
  f32x4 o[16];
#pragma unroll
  for (int df = 0; df < 16; ++df) o[df] = zero4;
  float mrow[4], lrow[4];
#pragma unroll
  for (int r = 0; r < 4; ++r) {
    mrow[r] = -__builtin_inff();
    lrow[r] = 0.f;
  }

  const char* kbase = (const char*)(kin + (size_t)b * Nn * Dd);
  const char* vbase = (const char*)(vt + (size_t)b * Dd * Nn);

  for (int t = 0; t < ntiles; ++t) {
    const int k0 = t * 64;
    // stage K tile: 32KB, 8 issues; source pre-swizzled so linear LDS holds swizzled layout
#pragma unroll
    for (int i = 0; i < 8; ++i) {
      int p = i * 4096 + tid * 16;
      int row = p >> 9;
      int src = p ^ ((row & 7) << 4);
      gl_lds16(kbase + (size_t)k0 * 512 + src, Ks + p);
    }
    // stage V^T tile rows: d in 0..255, 128B per row
#pragma unroll
    for (int i = 0; i < 8; ++i) {
      int p = i * 4096 + tid * 16;
      int row = p >> 7;
      int inrow = (p & 127) ^ ((row & 7) << 4);
      gl_lds16(vbase + ((size_t)row * Nn + k0) * 2 + inrow, Vs + p);
    }
    __syncthreads();

    // S = Q K^T  (two MFMAs per step: hi + lo)
    f32x4 s[4];
#pragma unroll
    for (int nf = 0; nf < 4; ++nf) {
      f32x4 a = zero4;
      int key = nf * 16 + l15;
      if (!uni) {
#pragma unroll
        for (int kt = 0; kt < 8; ++kt) {
          int byte = (key * 512 + kt * 64 + lq * 16) ^ ((key & 7) << 4);
          short8 kf = *(const short8*)(Ks + byte);
          a = mfma16(qh[kt], kf, a);
          a = mfma16(ql[kt], kf, a);
        }
        if (k0 + key >= L) {
          a[0] = -1e6f; a[1] = -1e6f; a[2] = -1e6f; a[3] = -1e6f;
        }
      }
      s[nf] = a;
    }

    // online softmax (rows = lq*4+r, reduce across the 16 lanes of each row group)
    float scale[4];
#pragma unroll
    for (int r = 0; r < 4; ++r) {
      float mx = fmaxf(fmaxf(s[0][r], s[1][r]), fmaxf(s[2][r], s[3][r]));
      mx = fmaxf(mx, __shfl_xor(mx, 1));
      mx = fmaxf(mx, __shfl_xor(mx, 2));
      mx = fmaxf(mx, __shfl_xor(mx, 4));
      mx = fmaxf(mx, __shfl_xor(mx, 8));
      float mnew = fmaxf(mrow[r], mx);
      float sc = __expf(mrow[r] - mnew);
      mrow[r] = mnew;
      scale[r] = sc;
      float sum = 0.f;
#pragma unroll
      for (int nf = 0; nf < 4; ++nf) {
        float p_ = __expf(s[nf][r] - mnew);
        s[nf][r] = p_;
        sum += p_;
      }
      sum += __shfl_xor(sum, 1);
      sum += __shfl_xor(sum, 2);
      sum += __shfl_xor(sum, 4);
      sum += __shfl_xor(sum, 8);
      lrow[r] = lrow[r] * sc + sum;
    }
#pragma unroll
    for (int df = 0; df < 16; ++df)
#pragma unroll
      for (int r = 0; r < 4; ++r) o[df][r] *= scale[r];

    // P (C-layout) -> LDS -> A-layout fragments
#pragma unroll
    for (int nf = 0; nf < 4; ++nf)
#pragma unroll
      for (int r = 0; r < 4; ++r)
        Ps[wave][(lq * 4 + r) * 72 + nf * 16 + l15] = f2bf(s[nf][r]);

#pragma unroll
    for (int kt = 0; kt < 2; ++kt) {
      short8 pa = *(const short8*)((const char*)&Ps[wave][0] + l15 * 144 + kt * 64 + lq * 16);
#pragma unroll
      for (int df = 0; df < 16; ++df) {
        int d = df * 16 + l15;
        int byte = (d * 128 + kt * 64 + lq * 16) ^ ((d & 7) << 4);
        short8 vf = *(const short8*)(Vs + byte);
        o[df] = mfma16(pa, vf, o[df]);
      }
    }
    __syncthreads();
  }

  // epilogue: divide by l, store f32
#pragma unroll
  for (int r = 0; r < 4; ++r) {
    float inv = 1.f / lrow[r];
    size_t qq = (size_t)b * Nn + q0 + wave * 16 + lq * 4 + r;
#pragma unroll
    for (int df = 0; df < 16; ++df) out[qq * Dd + df * 16 + l15] = o[df][r] * inv;
  }
}

// ---------- launch ----------
extern "C" void kernel_launch(void* const* d_in, const int* in_sizes, int n_in,
                              void* d_out, int out_size, void* d_ws, size_t ws_size,
                              hipStream_t stream) {
  const float* x = (const float*)d_in[0];
  const int* vlen = (const int*)d_in[1];
  const float* Wq = (const float*)d_in[2];
  const float* bq = (const float*)d_in[3];
  const float* Wk = (const float*)d_in[4];
  const float* bk = (const float*)d_in[5];
  const float* Wv = (const float*)d_in[6];
  const float* bv = (const float*)d_in[7];
  float* out = (float*)d_out;
  char* ws = (char*)d_ws;

  // workspace layout (bytes): qhi 16MB | qlo 16MB | K 16MB | Vt 16MB | Wsp 1.125MB  (~68.3MB)
  unsigned short* qhi = (unsigned short*)(ws);
  unsigned short* qlo = (unsigned short*)(ws + 16777216);
  unsigned short* kk = (unsigned short*)(ws + 33554432);
  unsigned short* vt = (unsigned short*)(ws + 50331648);
  unsigned short* wsp = (unsigned short*)(ws + 67108864);
  // xhi/xlo scratch lives in d_out (exactly 32MB; fully overwritten by k_attn at the end)
  unsigned short* xhi = (unsigned short*)d_out;
  unsigned short* xlo = xhi + (size_t)Bb * Nn * Cc;

  k_split_x<<<8192, 256, 0, stream>>>(x, xhi, xlo);
  k_split_w<<<768, 256, 0, stream>>>(Wq, Wk, Wv, wsp);
  k_qkv<<<dim3(256, 2, 3), 256, 0, stream>>>(xhi, xlo, wsp, bq, bk, bv, qhi, qlo, kk, vt);
  k_attn<<<512, 256, 0, stream>>>(qhi, qlo, kk, vt, vlen, out);
}

// Round 3
// 246.744 us; speedup vs baseline: 1.0450x; 1.0450x over previous
//
#include <hip/hip_runtime.h>
#include <hip/hip_bf16.h>
#include <stdint.h>

typedef __attribute__((ext_vector_type(8))) _Float16 half8;
typedef __attribute__((ext_vector_type(4))) _Float16 half4;
typedef __attribute__((ext_vector_type(4))) float f32x4;
typedef __attribute__((ext_vector_type(4))) float float4v;

#define DEVI static __device__ __forceinline__

constexpr int Bb = 16, Nn = 2048, Cc = 256, Dd = 256;

DEVI unsigned short f2h_bits(float f) {
  _Float16 h = (_Float16)f;
  union { _Float16 h; unsigned short u; } c;
  c.h = h;
  return c.u;
}

DEVI void gl_lds16(const void* gsrc, void* ldst) {
  __builtin_amdgcn_global_load_lds(
      (const __attribute__((address_space(1))) unsigned int*)gsrc,
      (__attribute__((address_space(3))) unsigned int*)ldst, 16, 0, 0);
}

DEVI f32x4 mfma16h(half8 a, half8 b, f32x4 c) {
  return __builtin_amdgcn_mfma_f32_16x16x32_f16(a, b, c, 0, 0, 0);
}

// ---------- kernel 0a: x (f32) -> xh (fp16) ----------
__global__ void k_split_x(const float* __restrict__ x, _Float16* __restrict__ xh) {
  int i = blockIdx.x * 256 + threadIdx.x;  // 2097152 groups of 4 floats
  float4v v = reinterpret_cast<const float4v*>(x)[i];
  half4 h;
#pragma unroll
  for (int j = 0; j < 4; ++j) h[j] = (_Float16)v[j];
  reinterpret_cast<half4*>(xh)[i] = h;
}

// ---------- kernel 0b: W (f32) -> wh (fp16), [mat][d][c] ----------
__global__ void k_split_w(const float* __restrict__ wq, const float* __restrict__ wk,
                          const float* __restrict__ wv, _Float16* __restrict__ wh) {
  int i = blockIdx.x * 256 + threadIdx.x;  // 0 .. 196607
  int mat = i >> 16;
  int rem = i & 65535;
  const float* w = (mat == 0) ? wq : ((mat == 1) ? wk : wv);
  wh[(size_t)mat * 65536 + rem] = (_Float16)w[rem];
}

// ---------- kernel 1: QKV projection GEMM (fp16 in, f32 acc) ----------
// out[m,d] = sum_c x[m,c]*W[d,c] + b[d].  128x128 tile, BK=64, 4 waves, C=256 (4 kc iters).
__global__ __launch_bounds__(256, 2) void k_qkv(
    const _Float16* __restrict__ xh, const _Float16* __restrict__ wh,
    const float* __restrict__ bq, const float* __restrict__ bk, const float* __restrict__ bv,
    _Float16* __restrict__ qout, _Float16* __restrict__ kout, _Float16* __restrict__ vt) {
  __shared__ __align__(16) unsigned short smem[17408];  // staging 32KB; V-transpose 128x136

  const int tid = threadIdx.x;
  const int m0 = blockIdx.x * 128;
  const int n0 = blockIdx.y * 128;
  const int mat = blockIdx.z;
  const _Float16* wmat = wh + (size_t)mat * 65536;
  const int wave = tid >> 6, lane = tid & 63;
  const int wr = wave >> 1, wc = wave & 1;
  const int l15 = lane & 15, lq = lane >> 4;

  f32x4 zero4 = {0.f, 0.f, 0.f, 0.f};
  f32x4 acc[4][4];
#pragma unroll
  for (int a = 0; a < 4; ++a)
#pragma unroll
    for (int b2 = 0; b2 < 4; ++b2) acc[a][b2] = zero4;

  char* As = (char*)smem;          // [128 rows][128B], XOR-swizzled
  char* Bs = (char*)smem + 16384;  // [128 rows][128B], XOR-swizzled

  for (int kc = 0; kc < 4; ++kc) {
#pragma unroll
    for (int i = 0; i < 4; ++i) {
      int p = i * 4096 + tid * 16;
      int row = p >> 7;
      int src_in_row = (p & 127) ^ ((row & 7) << 4);
      const char* g = (const char*)(xh + (size_t)(m0 + row) * Cc + kc * 64) + src_in_row;
      gl_lds16(g, As + p);
    }
#pragma unroll
    for (int i = 0; i < 4; ++i) {
      int p = i * 4096 + tid * 16;
      int row = p >> 7;
      int src_in_row = (p & 127) ^ ((row & 7) << 4);
      const char* g = (const char*)(wmat + (size_t)(n0 + row) * Cc + kc * 64) + src_in_row;
      gl_lds16(g, Bs + p);
    }
    __syncthreads();
#pragma unroll
    for (int ks = 0; ks < 2; ++ks) {
      half8 af[4], bfr[4];
#pragma unroll
      for (int mf = 0; mf < 4; ++mf) {
        int row = wr * 64 + mf * 16 + l15;
        int byte = (row * 128 + ks * 64 + lq * 16) ^ ((row & 7) << 4);
        af[mf] = *(const half8*)(As + byte);
      }
#pragma unroll
      for (int nf = 0; nf < 4; ++nf) {
        int row = wc * 64 + nf * 16 + l15;
        int byte = (row * 128 + ks * 64 + lq * 16) ^ ((row & 7) << 4);
        bfr[nf] = *(const half8*)(Bs + byte);
      }
#pragma unroll
      for (int mf = 0; mf < 4; ++mf)
#pragma unroll
        for (int nf = 0; nf < 4; ++nf) acc[mf][nf] = mfma16h(af[mf], bfr[nf], acc[mf][nf]);
    }
    __syncthreads();
  }

  const float* bias = (mat == 0) ? bq : ((mat == 1) ? bk : bv);
  if (mat < 2) {
    _Float16* oo = (mat == 0) ? qout : kout;
#pragma unroll
    for (int nf = 0; nf < 4; ++nf) {
      int col = n0 + wc * 64 + nf * 16 + l15;
      float bval = bias[col];
#pragma unroll
      for (int mf = 0; mf < 4; ++mf) {
        int grow = m0 + wr * 64 + mf * 16 + lq * 4;
#pragma unroll
        for (int r = 0; r < 4; ++r)
          oo[(size_t)(grow + r) * Dd + col] = (_Float16)(acc[mf][nf][r] + bval);
      }
    }
  } else {
    // V: transpose tile through LDS -> coalesced stores into vt[B][D][N]
    __syncthreads();
#pragma unroll
    for (int nf = 0; nf < 4; ++nf) {
      int dl = wc * 64 + nf * 16 + l15;
      float bval = bias[n0 + dl];
#pragma unroll
      for (int mf = 0; mf < 4; ++mf) {
        int nl = wr * 64 + mf * 16 + lq * 4;
#pragma unroll
        for (int r = 0; r < 4; ++r) smem[dl * 136 + nl + r] = f2h_bits(acc[mf][nf][r] + bval);
      }
    }
    __syncthreads();
    const int bbat = m0 >> 11, tok0 = m0 & 2047;
#pragma unroll
    for (int pss = 0; pss < 8; ++pss) {
      int idx = pss * 256 + tid;  // 16B unit index; 2048 total
      int dl = idx >> 4;
      int cu = idx & 15;
      half8 vval = *(const half8*)((const char*)smem + dl * 272 + cu * 16);
      size_t off = ((size_t)bbat * Dd + n0 + dl) * Nn + tok0 + cu * 8;
      *(half8*)(vt + off) = vval;
    }
  }
}

// ---------- kernel 2: flash attention ----------
// 256 blocks (1/CU, XCD-pinned: XCD g owns batches {g,g+8}), 4 waves, BQ=128
// (32 q-rows/wave via 2 A-frags), KV tile 64, double-buffered staging.
__global__ __launch_bounds__(256, 1) void k_attn(
    const _Float16* __restrict__ qg, const _Float16* __restrict__ kin,
    const _Float16* __restrict__ vt, const int* __restrict__ vlen,
    float* __restrict__ out) {
  __shared__ __align__(16) char KV[2][65536];              // per buf: K 32KB | V 32KB
  __shared__ __align__(16) unsigned short Ps[4][32 * 72];  // per-wave P [32 q][64+8 k]

  const int tid = threadIdx.x;
  const int wave = tid >> 6, lane = tid & 63;
  const int l15 = lane & 15, lq = lane >> 4;
  const int id = blockIdx.x;
  const int g = id & 7;
  const int j = id >> 3;           // 0..31
  const int b = g + 8 * (j >> 4);  // batches g, g+8
  const int q0 = (j & 15) * 128;
  const int L = vlen[b];
  const bool uni = (L == 0);
  const int Lk = uni ? Nn : L;
  const int nt = (Lk + 63) >> 6;

  // Q fragments: qf in {0,1}, rows = q0 + wave*32 + qf*16 + l15
  half8 qf_[2][8];
#pragma unroll
  for (int qf = 0; qf < 2; ++qf) {
    const size_t qrow = (size_t)b * Nn + q0 + wave * 32 + qf * 16 + l15;
#pragma unroll
    for (int kt = 0; kt < 8; ++kt)
      qf_[qf][kt] = *(const half8*)(qg + qrow * Dd + kt * 32 + lq * 8);
  }

  f32x4 zero4 = {0.f, 0.f, 0.f, 0.f};
  f32x4 o[2][16];
#pragma unroll
  for (int qf = 0; qf < 2; ++qf)
#pragma unroll
    for (int df = 0; df < 16; ++df) o[qf][df] = zero4;
  float mrow[2][4], lrow[2][4];
#pragma unroll
  for (int qf = 0; qf < 2; ++qf)
#pragma unroll
    for (int r = 0; r < 4; ++r) {
      mrow[qf][r] = -__builtin_inff();
      lrow[qf][r] = 0.f;
    }

  const char* kbase = (const char*)(kin + (size_t)b * Nn * Dd);
  const char* vbase = (const char*)(vt + (size_t)b * Dd * Nn);

  auto STAGE = [&](int buf, int t) {
    char* dst = (char*)KV[buf];
    const int k0 = t * 64;
#pragma unroll
    for (int i = 0; i < 8; ++i) {  // K: 64 keys x 512B
      int p = i * 4096 + tid * 16;
      int row = p >> 9;
      int src = p ^ ((row & 7) << 4);
      gl_lds16(kbase + (size_t)k0 * 512 + src, dst + p);
    }
#pragma unroll
    for (int i = 0; i < 8; ++i) {  // V^T: 256 d x 128B
      int p = i * 4096 + tid * 16;
      int row = p >> 7;
      int inrow = (p & 127) ^ ((row & 7) << 4);
      gl_lds16(vbase + ((size_t)row * Nn + k0) * 2 + inrow, dst + 32768 + p);
    }
  };

  STAGE(0, 0);
  __syncthreads();

  for (int t = 0; t < nt; ++t) {
    const int cur = t & 1;
    if (t + 1 < nt) STAGE(cur ^ 1, t + 1);  // prefetch next tile (drained by barrier below)
    const char* Ks = (const char*)KV[cur];
    const char* Vs = (const char*)KV[cur] + 32768;
    const int k0 = t * 64;

    // S = Q K^T (one MFMA per K-fragment per qf)
    f32x4 s[2][4];
    if (!uni) {
#pragma unroll
      for (int nf = 0; nf < 4; ++nf) {
        int key = nf * 16 + l15;
        f32x4 a0 = zero4, a1 = zero4;
#pragma unroll
        for (int kt = 0; kt < 8; ++kt) {
          int byte = (key * 512 + kt * 64 + lq * 16) ^ ((key & 7) << 4);
          half8 kf = *(const half8*)(Ks + byte);
          a0 = mfma16h(qf_[0][kt], kf, a0);
          a1 = mfma16h(qf_[1][kt], kf, a1);
        }
        if (k0 + key >= L) {
          a0[0] = -1e6f; a0[1] = -1e6f; a0[2] = -1e6f; a0[3] = -1e6f;
          a1[0] = -1e6f; a1[1] = -1e6f; a1[2] = -1e6f; a1[3] = -1e6f;
        }
        s[0][nf] = a0;
        s[1][nf] = a1;
      }
    } else {
#pragma unroll
      for (int qf = 0; qf < 2; ++qf)
#pragma unroll
        for (int nf = 0; nf < 4; ++nf) s[qf][nf] = zero4;
    }

    // online softmax: rows = qf*16 + lq*4 + r, reduce over 16 lanes (l15)
    float scale[2][4];
#pragma unroll
    for (int qf = 0; qf < 2; ++qf)
#pragma unroll
      for (int r = 0; r < 4; ++r) {
        float mx = fmaxf(fmaxf(s[qf][0][r], s[qf][1][r]), fmaxf(s[qf][2][r], s[qf][3][r]));
        mx = fmaxf(mx, __shfl_xor(mx, 1));
        mx = fmaxf(mx, __shfl_xor(mx, 2));
        mx = fmaxf(mx, __shfl_xor(mx, 4));
        mx = fmaxf(mx, __shfl_xor(mx, 8));
        float mnew = fmaxf(mrow[qf][r], mx);
        float sc = __expf(mrow[qf][r] - mnew);
        mrow[qf][r] = mnew;
        scale[qf][r] = sc;
        float sum = 0.f;
#pragma unroll
        for (int nf = 0; nf < 4; ++nf) {
          float p_ = __expf(s[qf][nf][r] - mnew);
          s[qf][nf][r] = p_;
          sum += p_;
        }
        sum += __shfl_xor(sum, 1);
        sum += __shfl_xor(sum, 2);
        sum += __shfl_xor(sum, 4);
        sum += __shfl_xor(sum, 8);
        lrow[qf][r] = lrow[qf][r] * sc + sum;
      }
#pragma unroll
    for (int qf = 0; qf < 2; ++qf)
#pragma unroll
      for (int df = 0; df < 16; ++df)
#pragma unroll
        for (int r = 0; r < 4; ++r) o[qf][df][r] *= scale[qf][r];

    // P (C-layout) -> per-wave LDS -> A-layout fragments
#pragma unroll
    for (int qf = 0; qf < 2; ++qf)
#pragma unroll
      for (int nf = 0; nf < 4; ++nf)
#pragma unroll
        for (int r = 0; r < 4; ++r)
          Ps[wave][(qf * 16 + lq * 4 + r) * 72 + nf * 16 + l15] = f2h_bits(s[qf][nf][r]);

#pragma unroll
    for (int kt = 0; kt < 2; ++kt) {
      half8 pa0 = *(const half8*)((const char*)&Ps[wave][0] + (l15)*144 + kt * 64 + lq * 16);
      half8 pa1 = *(const half8*)((const char*)&Ps[wave][0] + (16 + l15) * 144 + kt * 64 + lq * 16);
#pragma unroll
      for (int df = 0; df < 16; ++df) {
        int d = df * 16 + l15;
        int byte = (d * 128 + kt * 64 + lq * 16) ^ ((d & 7) << 4);
        half8 vf = *(const half8*)(Vs + byte);
        o[0][df] = mfma16h(pa0, vf, o[0][df]);
        o[1][df] = mfma16h(pa1, vf, o[1][df]);
      }
    }
    __syncthreads();  // drains prefetch (vmcnt 0) + protects buf reuse
  }

  // epilogue
#pragma unroll
  for (int qf = 0; qf < 2; ++qf)
#pragma unroll
    for (int r = 0; r < 4; ++r) {
      float inv = 1.f / lrow[qf][r];
      size_t qq = (size_t)b * Nn + q0 + wave * 32 + qf * 16 + lq * 4 + r;
#pragma unroll
      for (int df = 0; df < 16; ++df) out[qq * Dd + df * 16 + l15] = o[qf][df][r] * inv;
    }
}

// ---------- launch ----------
extern "C" void kernel_launch(void* const* d_in, const int* in_sizes, int n_in,
                              void* d_out, int out_size, void* d_ws, size_t ws_size,
                              hipStream_t stream) {
  const float* x = (const float*)d_in[0];
  const int* vlen = (const int*)d_in[1];
  const float* Wq = (const float*)d_in[2];
  const float* bq = (const float*)d_in[3];
  const float* Wk = (const float*)d_in[4];
  const float* bk = (const float*)d_in[5];
  const float* Wv = (const float*)d_in[6];
  const float* bv = (const float*)d_in[7];
  float* out = (float*)d_out;
  char* ws = (char*)d_ws;

  // workspace: q 16MB | k 16MB | vt 16MB | wh 384KB  (~48.4MB)
  _Float16* qh = (_Float16*)(ws);
  _Float16* kk = (_Float16*)(ws + 16777216);
  _Float16* vt = (_Float16*)(ws + 33554432);
  _Float16* wh = (_Float16*)(ws + 50331648);
  // xh scratch lives in d_out (16MB of 32MB; fully overwritten by k_attn)
  _Float16* xh = (_Float16*)d_out;

  k_split_x<<<8192, 256, 0, stream>>>(x, xh);
  k_split_w<<<768, 256, 0, stream>>>(Wq, Wk, Wv, wh);
  k_qkv<<<dim3(256, 2, 3), 256, 0, stream>>>(xh, wh, bq, bk, bv, qh, kk, vt);
  k_attn<<<256, 256, 0, stream>>>(qh, kk, vt, vlen, out);
}

// Round 4
// 155.263 us; speedup vs baseline: 1.6607x; 1.5892x over previous
//
#include <hip/hip_runtime.h>
#include <hip/hip_bf16.h>
#include <stdint.h>

typedef __attribute__((ext_vector_type(8))) _Float16 half8;
typedef __attribute__((ext_vector_type(4))) _Float16 half4;
typedef __attribute__((ext_vector_type(4))) float f32x4;
typedef __attribute__((ext_vector_type(4))) float float4v;

#define DEVI static __device__ __forceinline__

constexpr int Bb = 16, Nn = 2048, Cc = 256, Dd = 256;

DEVI unsigned short f2h_bits(float f) {
  _Float16 h = (_Float16)f;
  union { _Float16 h; unsigned short u; } c;
  c.h = h;
  return c.u;
}

DEVI void gl_lds16(const void* gsrc, void* ldst) {
  __builtin_amdgcn_global_load_lds(
      (const __attribute__((address_space(1))) unsigned int*)gsrc,
      (__attribute__((address_space(3))) unsigned int*)ldst, 16, 0, 0);
}

DEVI f32x4 mfma16h(half8 a, half8 b, f32x4 c) {
  return __builtin_amdgcn_mfma_f32_16x16x32_f16(a, b, c, 0, 0, 0);
}

// ---------- kernel 0a: x (f32) -> xh (fp16) ----------
__global__ void k_split_x(const float* __restrict__ x, _Float16* __restrict__ xh) {
  int i = blockIdx.x * 256 + threadIdx.x;  // 2097152 groups of 4 floats
  float4v v = reinterpret_cast<const float4v*>(x)[i];
  half4 h;
#pragma unroll
  for (int j = 0; j < 4; ++j) h[j] = (_Float16)v[j];
  reinterpret_cast<half4*>(xh)[i] = h;
}

// ---------- kernel 0b: W (f32) -> wh (fp16), [mat][d][c] ----------
__global__ void k_split_w(const float* __restrict__ wq, const float* __restrict__ wk,
                          const float* __restrict__ wv, _Float16* __restrict__ wh) {
  int i = blockIdx.x * 256 + threadIdx.x;  // 0 .. 196607
  int mat = i >> 16;
  int rem = i & 65535;
  const float* w = (mat == 0) ? wq : ((mat == 1) ? wk : wv);
  wh[(size_t)mat * 65536 + rem] = (_Float16)w[rem];
}

// ---------- kernel 1: QKV projection GEMM (fp16 in, f32 acc) ----------
__global__ __launch_bounds__(256, 2) void k_qkv(
    const _Float16* __restrict__ xh, const _Float16* __restrict__ wh,
    const float* __restrict__ bq, const float* __restrict__ bk, const float* __restrict__ bv,
    _Float16* __restrict__ qout, _Float16* __restrict__ kout, _Float16* __restrict__ vt) {
  __shared__ __align__(16) unsigned short smem[17408];  // staging 32KB; V-transpose 128x136

  const int tid = threadIdx.x;
  const int m0 = blockIdx.x * 128;
  const int n0 = blockIdx.y * 128;
  const int mat = blockIdx.z;
  const _Float16* wmat = wh + (size_t)mat * 65536;
  const int wave = tid >> 6, lane = tid & 63;
  const int wr = wave >> 1, wc = wave & 1;
  const int l15 = lane & 15, lq = lane >> 4;

  f32x4 zero4 = {0.f, 0.f, 0.f, 0.f};
  f32x4 acc[4][4];
#pragma unroll
  for (int a = 0; a < 4; ++a)
#pragma unroll
    for (int b2 = 0; b2 < 4; ++b2) acc[a][b2] = zero4;

  char* As = (char*)smem;          // [128 rows][128B], XOR-swizzled
  char* Bs = (char*)smem + 16384;  // [128 rows][128B], XOR-swizzled

  for (int kc = 0; kc < 4; ++kc) {
#pragma unroll
    for (int i = 0; i < 4; ++i) {
      int p = i * 4096 + tid * 16;
      int row = p >> 7;
      int src_in_row = (p & 127) ^ ((row & 7) << 4);
      const char* g = (const char*)(xh + (size_t)(m0 + row) * Cc + kc * 64) + src_in_row;
      gl_lds16(g, As + p);
    }
#pragma unroll
    for (int i = 0; i < 4; ++i) {
      int p = i * 4096 + tid * 16;
      int row = p >> 7;
      int src_in_row = (p & 127) ^ ((row & 7) << 4);
      const char* g = (const char*)(wmat + (size_t)(n0 + row) * Cc + kc * 64) + src_in_row;
      gl_lds16(g, Bs + p);
    }
    __syncthreads();
#pragma unroll
    for (int ks = 0; ks < 2; ++ks) {
      half8 af[4], bfr[4];
#pragma unroll
      for (int mf = 0; mf < 4; ++mf) {
        int row = wr * 64 + mf * 16 + l15;
        int byte = (row * 128 + ks * 64 + lq * 16) ^ ((row & 7) << 4);
        af[mf] = *(const half8*)(As + byte);
      }
#pragma unroll
      for (int nf = 0; nf < 4; ++nf) {
        int row = wc * 64 + nf * 16 + l15;
        int byte = (row * 128 + ks * 64 + lq * 16) ^ ((row & 7) << 4);
        bfr[nf] = *(const half8*)(Bs + byte);
      }
#pragma unroll
      for (int mf = 0; mf < 4; ++mf)
#pragma unroll
        for (int nf = 0; nf < 4; ++nf) acc[mf][nf] = mfma16h(af[mf], bfr[nf], acc[mf][nf]);
    }
    __syncthreads();
  }

  const float* bias = (mat == 0) ? bq : ((mat == 1) ? bk : bv);
  if (mat < 2) {
    _Float16* oo = (mat == 0) ? qout : kout;
#pragma unroll
    for (int nf = 0; nf < 4; ++nf) {
      int col = n0 + wc * 64 + nf * 16 + l15;
      float bval = bias[col];
#pragma unroll
      for (int mf = 0; mf < 4; ++mf) {
        int grow = m0 + wr * 64 + mf * 16 + lq * 4;
#pragma unroll
        for (int r = 0; r < 4; ++r)
          oo[(size_t)(grow + r) * Dd + col] = (_Float16)(acc[mf][nf][r] + bval);
      }
    }
  } else {
    // V: transpose tile through LDS -> coalesced stores into vt[B][D][N]
    __syncthreads();
#pragma unroll
    for (int nf = 0; nf < 4; ++nf) {
      int dl = wc * 64 + nf * 16 + l15;
      float bval = bias[n0 + dl];
#pragma unroll
      for (int mf = 0; mf < 4; ++mf) {
        int nl = wr * 64 + mf * 16 + lq * 4;
#pragma unroll
        for (int r = 0; r < 4; ++r) smem[dl * 136 + nl + r] = f2h_bits(acc[mf][nf][r] + bval);
      }
    }
    __syncthreads();
    const int bbat = m0 >> 11, tok0 = m0 & 2047;
#pragma unroll
    for (int pss = 0; pss < 8; ++pss) {
      int idx = pss * 256 + tid;
      int dl = idx >> 4;
      int cu = idx & 15;
      half8 vval = *(const half8*)((const char*)smem + dl * 272 + cu * 16);
      size_t off = ((size_t)bbat * Dd + n0 + dl) * Nn + tok0 + cu * 8;
      *(half8*)(vt + off) = vval;
    }
  }
}

// ---------- kernel 2: flash attention ----------
// 256 blocks (1/CU, XCD-pinned), 512 threads = 8 waves x 16 q-rows (BQ=128),
// KV tile 64, double-buffered LDS staging with COUNTED vmcnt (loads for tile
// t+1 stay in flight across the barrier; only tile t's 8 loads are drained).
__global__ __launch_bounds__(512, 2) void k_attn(
    const _Float16* __restrict__ qg, const _Float16* __restrict__ kin,
    const _Float16* __restrict__ vt, const int* __restrict__ vlen,
    float* __restrict__ out) {
  __shared__ __align__(16) char KV[2][65536];              // per buf: K 32KB | V 32KB
  __shared__ __align__(16) unsigned short Ps[8][16 * 72];  // per-wave P [16 q][64+8 k]

  const int tid = threadIdx.x;
  const int wave = tid >> 6, lane = tid & 63;
  const int l15 = lane & 15, lq = lane >> 4;
  const int id = blockIdx.x;
  const int g = id & 7;            // XCD (HW round-robin)
  const int j = id >> 3;           // 0..31
  const int b = g + 8 * (j >> 4);  // XCD g owns batches {g, g+8} (K+V = 4MB = one L2)
  const int q0 = (j & 15) * 128;
  const int L = vlen[b];
  const bool uni = (L == 0);
  const int Lk = uni ? Nn : L;
  const int nt = (Lk + 63) >> 6;

  // Q fragments: rows = q0 + wave*16 + l15
  const size_t qrow = (size_t)b * Nn + q0 + wave * 16 + l15;
  half8 qf_[8];
#pragma unroll
  for (int kt = 0; kt < 8; ++kt)
    qf_[kt] = *(const half8*)(qg + qrow * Dd + kt * 32 + lq * 8);

  f32x4 zero4 = {0.f, 0.f, 0.f, 0.f};
  f32x4 o[16];
#pragma unroll
  for (int df = 0; df < 16; ++df) o[df] = zero4;
  float mrow[4], lrow[4];
#pragma unroll
  for (int r = 0; r < 4; ++r) {
    mrow[r] = -__builtin_inff();
    lrow[r] = 0.f;
  }

  const char* kbase = (const char*)(kin + (size_t)b * Nn * Dd);
  const char* vbase = (const char*)(vt + (size_t)b * Dd * Nn);

  // 8 gl_lds per wave per STAGE (512 threads x 16B x 8 = 64KB)
  auto STAGE = [&](int buf, int t) {
    char* dst = (char*)KV[buf];
    const int k0 = t * 64;
#pragma unroll
    for (int i = 0; i < 4; ++i) {  // K: 64 keys x 512B
      int p = i * 8192 + tid * 16;
      int row = p >> 9;
      int src = p ^ ((row & 7) << 4);
      gl_lds16(kbase + (size_t)k0 * 512 + src, dst + p);
    }
#pragma unroll
    for (int i = 0; i < 4; ++i) {  // V^T: 256 d x 128B
      int p = i * 8192 + tid * 16;
      int row = p >> 7;
      int inrow = (p & 127) ^ ((row & 7) << 4);
      gl_lds16(vbase + ((size_t)row * Nn + k0) * 2 + inrow, dst + 32768 + p);
    }
  };

  STAGE(0, 0);

  for (int t = 0; t < nt; ++t) {
    const int cur = t & 1;
    if (t + 1 < nt) {
      STAGE(cur ^ 1, t + 1);  // 8 new loads in flight (stay across barrier)
      asm volatile("s_waitcnt vmcnt(8)" ::: "memory");  // drain only tile t's 8
    } else {
      asm volatile("s_waitcnt vmcnt(0)" ::: "memory");
    }
    asm volatile("s_barrier" ::: "memory");

    const char* Ks = (const char*)KV[cur];
    const char* Vs = (const char*)KV[cur] + 32768;
    const int k0 = t * 64;

    // S = Q K^T : kt-outer / nf-inner -> 4 independent accumulator chains
    f32x4 s[4];
#pragma unroll
    for (int nf = 0; nf < 4; ++nf) s[nf] = zero4;
    if (!uni) {
      __builtin_amdgcn_s_setprio(1);
#pragma unroll
      for (int kt = 0; kt < 8; ++kt) {
        half8 kf[4];
#pragma unroll
        for (int nf = 0; nf < 4; ++nf) {
          int key = nf * 16 + l15;
          int byte = (key * 512 + kt * 64 + lq * 16) ^ ((key & 7) << 4);
          kf[nf] = *(const half8*)(Ks + byte);
        }
#pragma unroll
        for (int nf = 0; nf < 4; ++nf) s[nf] = mfma16h(qf_[kt], kf[nf], s[nf]);
      }
      __builtin_amdgcn_s_setprio(0);
      if (k0 + 64 > L) {
#pragma unroll
        for (int nf = 0; nf < 4; ++nf) {
          int key = nf * 16 + l15;
          if (k0 + key >= L) {
            s[nf][0] = -1e6f; s[nf][1] = -1e6f; s[nf][2] = -1e6f; s[nf][3] = -1e6f;
          }
        }
      }
    }

    // online softmax: rows = lq*4 + r, reduce across 16 lanes (l15)
    float scale[4];
#pragma unroll
    for (int r = 0; r < 4; ++r) {
      float mx = fmaxf(fmaxf(s[0][r], s[1][r]), fmaxf(s[2][r], s[3][r]));
      mx = fmaxf(mx, __shfl_xor(mx, 1));
      mx = fmaxf(mx, __shfl_xor(mx, 2));
      mx = fmaxf(mx, __shfl_xor(mx, 4));
      mx = fmaxf(mx, __shfl_xor(mx, 8));
      float mnew = fmaxf(mrow[r], mx);
      float sc = __expf(mrow[r] - mnew);
      mrow[r] = mnew;
      scale[r] = sc;
      float sum = 0.f;
#pragma unroll
      for (int nf = 0; nf < 4; ++nf) {
        float p_ = __expf(s[nf][r] - mnew);
        s[nf][r] = p_;
        sum += p_;
      }
      sum += __shfl_xor(sum, 1);
      sum += __shfl_xor(sum, 2);
      sum += __shfl_xor(sum, 4);
      sum += __shfl_xor(sum, 8);
      lrow[r] = lrow[r] * sc + sum;
    }
#pragma unroll
    for (int df = 0; df < 16; ++df)
#pragma unroll
      for (int r = 0; r < 4; ++r) o[df][r] *= scale[r];

    // P (C-layout) -> per-wave LDS -> A-layout fragments
#pragma unroll
    for (int nf = 0; nf < 4; ++nf)
#pragma unroll
      for (int r = 0; r < 4; ++r)
        Ps[wave][(lq * 4 + r) * 72 + nf * 16 + l15] = f2h_bits(s[nf][r]);

    __builtin_amdgcn_s_setprio(1);
#pragma unroll
    for (int kt = 0; kt < 2; ++kt) {
      half8 pa = *(const half8*)((const char*)&Ps[wave][0] + l15 * 144 + kt * 64 + lq * 16);
#pragma unroll
      for (int df = 0; df < 16; ++df) {
        int d = df * 16 + l15;
        int byte = (d * 128 + kt * 64 + lq * 16) ^ ((d & 7) << 4);
        half8 vf = *(const half8*)(Vs + byte);
        o[df] = mfma16h(pa, vf, o[df]);
      }
    }
    __builtin_amdgcn_s_setprio(0);

    asm volatile("s_barrier" ::: "memory");  // protect buf before next overwrite
  }

  // epilogue: divide by l, store f32
#pragma unroll
  for (int r = 0; r < 4; ++r) {
    float inv = 1.f / lrow[r];
    size_t qq = (size_t)b * Nn + q0 + wave * 16 + lq * 4 + r;
#pragma unroll
    for (int df = 0; df < 16; ++df) out[qq * Dd + df * 16 + l15] = o[df][r] * inv;
  }
}

// ---------- launch ----------
extern "C" void kernel_launch(void* const* d_in, const int* in_sizes, int n_in,
                              void* d_out, int out_size, void* d_ws, size_t ws_size,
                              hipStream_t stream) {
  const float* x = (const float*)d_in[0];
  const int* vlen = (const int*)d_in[1];
  const float* Wq = (const float*)d_in[2];
  const float* bq = (const float*)d_in[3];
  const float* Wk = (const float*)d_in[4];
  const float* bk = (const float*)d_in[5];
  const float* Wv = (const float*)d_in[6];
  const float* bv = (const float*)d_in[7];
  float* out = (float*)d_out;
  char* ws = (char*)d_ws;

  // workspace: q 16MB | k 16MB | vt 16MB | wh 384KB  (~48.4MB)
  _Float16* qh = (_Float16*)(ws);
  _Float16* kk = (_Float16*)(ws + 16777216);
  _Float16* vt = (_Float16*)(ws + 33554432);
  _Float16* wh = (_Float16*)(ws + 50331648);
  // xh scratch lives in d_out (16MB of 32MB; fully overwritten by k_attn)
  _Float16* xh = (_Float16*)d_out;

  k_split_x<<<8192, 256, 0, stream>>>(x, xh);
  k_split_w<<<768, 256, 0, stream>>>(Wq, Wk, Wv, wh);
  k_qkv<<<dim3(256, 2, 3), 256, 0, stream>>>(xh, wh, bq, bk, bv, qh, kk, vt);
  k_attn<<<256, 512, 0, stream>>>(qh, kk, vt, vlen, out);
}